// Round 7
// baseline (513.467 us; speedup 1.0000x reference)
//
#include <hip/hip_runtime.h>

// GCN VGAE encoder, pull-based. N=50000 (<2^16: rows pack in 16 bits), E=1.6M.
// out[i] = dis[i] * (hs[i] + sum_{j->i} hs[j]),  hs = dis .* (x@W)
// CSR build: coarse-bucket (256 nodes) counting sort with XCD-clean writes.
// GEMMs: per-wave row-tile staged in LDS (coalesced load, broadcast read).

#define NBMAX 256

__device__ __forceinline__ float4 f4add(float4 a, float4 b) {
    return make_float4(a.x + b.x, a.y + b.y, a.z + b.z, a.w + b.w);
}

__global__ __launch_bounds__(256) void k_hist(const int* __restrict__ col,
                                              int* __restrict__ bcnt, int e) {
    __shared__ int h[NBMAX];
    for (int i = threadIdx.x; i < NBMAX; i += 256) h[i] = 0;
    __syncthreads();
    for (int i = blockIdx.x * 256 + threadIdx.x; i < e; i += gridDim.x * 256)
        atomicAdd(&h[col[i] >> 8], 1);
    __syncthreads();
    for (int i = threadIdx.x; i < NBMAX; i += 256)
        if (h[i]) atomicAdd(bcnt + i, h[i]);
}

__global__ __launch_bounds__(256) void k_scanb(const int* __restrict__ bcnt,
                                               int* __restrict__ bbase,
                                               int* __restrict__ bcur,
                                               int* __restrict__ rowptr,
                                               int nb, int n, int e) {
    __shared__ int s[256];
    int t = threadIdx.x;
    int v = (t < nb) ? bcnt[t] : 0;
    s[t] = v;
    __syncthreads();
    for (int off = 1; off < 256; off <<= 1) {
        int u = (t >= off) ? s[t - off] : 0;
        __syncthreads();
        s[t] += u;
        __syncthreads();
    }
    int excl = s[t] - v;
    if (t <= nb) bbase[t] = (t < nb) ? excl : e;
    if (t < nb) bcur[t] = excl;
    if (t == 0) rowptr[n] = e;
}

__global__ __launch_bounds__(256) void k_tilesort(const int* __restrict__ row,
                                                  const int* __restrict__ col,
                                                  int* __restrict__ bcur,
                                                  int* __restrict__ binbuf,
                                                  int e, int chunk) {
    __shared__ int lh[NBMAX];
    int t0 = blockIdx.x * chunk;
    int t1 = t0 + chunk < e ? t0 + chunk : e;
    for (int i = threadIdx.x; i < NBMAX; i += 256) lh[i] = 0;
    __syncthreads();
    for (int i = t0 + threadIdx.x; i < t1; i += 256)
        atomicAdd(&lh[col[i] >> 8], 1);
    __syncthreads();
    for (int b = threadIdx.x; b < NBMAX; b += 256) {
        int c = lh[b];
        if (c) lh[b] = atomicAdd(bcur + b, c);
    }
    __syncthreads();
    for (int i = t0 + threadIdx.x; i < t1; i += 256) {
        int c = col[i];
        int pos = atomicAdd(&lh[c >> 8], 1);
        binbuf[pos] = row[i] | ((c & 255) << 16);
    }
}

__global__ __launch_bounds__(256) void k_build(const int* __restrict__ binbuf,
                                               const int* __restrict__ bbase,
                                               float* __restrict__ dis,
                                               int* __restrict__ rowptr,
                                               int* __restrict__ csr, int n) {
    __shared__ int lcnt[256], s[256], cur[256];
    int b = blockIdx.x;
    int t = threadIdx.x;
    int lo = bbase[b], hi = bbase[b + 1];
    int node0 = b << 8;
    int nloc = n - node0 < 256 ? n - node0 : 256;
    lcnt[t] = 0;
    __syncthreads();
    for (int k = lo + t; k < hi; k += 256)
        atomicAdd(&lcnt[(binbuf[k] >> 16) & 255], 1);
    __syncthreads();
    int v = lcnt[t];
    s[t] = v;
    __syncthreads();
    for (int off = 1; off < 256; off <<= 1) {
        int u = (t >= off) ? s[t - off] : 0;
        __syncthreads();
        s[t] += u;
        __syncthreads();
    }
    if (t < nloc) {
        int rp = lo + s[t] - v;
        rowptr[node0 + t] = rp;
        cur[t] = rp;
        dis[node0 + t] = rsqrtf((float)v + 1.0f);
    }
    __syncthreads();
    for (int k = lo + t; k < hi; k += 256) {
        int p = binbuf[k];
        int pos = atomicAdd(&cur[(p >> 16) & 255], 1);
        csr[pos] = p & 0xffff;
    }
}

// x[n,128] @ W[128,64] * dis -> hs1[n,64]. 64 rows/block, 16 rows/wave.
// Per-wave x-tile staged in LDS (coalesced float4), read back as broadcast.
__global__ __launch_bounds__(256) void k_gemm1(const float* __restrict__ x,
                                               const float* __restrict__ W,
                                               const float* __restrict__ dis,
                                               float* __restrict__ hs1, int n) {
    __shared__ float w4[64 * 33 * 4];      // W^T as float4 [ch][k4], stride 33
    __shared__ float4 xs[4][16 * 32];      // per-wave 16 rows x 32 float4
    for (int i = threadIdx.x; i < 128 * 64; i += 256) {
        int k = i >> 6, c = i & 63;
        w4[(c * 33 + (k >> 2)) * 4 + (k & 3)] = W[i];
    }
    int wid = threadIdx.x >> 6;
    int lane = threadIdx.x & 63;
    int r0 = blockIdx.x * 64 + wid * 16;
    const float4* x4 = (const float4*)x;
#pragma unroll
    for (int j = 0; j < 8; ++j) {
        int idx = j * 64 + lane;           // 0..511: (row, k4) = (idx>>5, idx&31)
        int rr = r0 + (idx >> 5);
        if (rr >= n) rr = n - 1;
        xs[wid][idx] = x4[(size_t)rr * 32 + (idx & 31)];
    }
    __syncthreads();
    int ch = lane;
    float acc[16];
#pragma unroll
    for (int r = 0; r < 16; ++r) acc[r] = 0.f;
    const float4* wl = (const float4*)w4;
    const float4* xw = xs[wid];
#pragma unroll 4
    for (int k4 = 0; k4 < 32; ++k4) {
        float4 wv = wl[ch * 33 + k4];
#pragma unroll
        for (int r = 0; r < 16; ++r) {
            float4 xv = xw[r * 32 + k4];   // wave-uniform -> LDS broadcast
            acc[r] = fmaf(xv.x, wv.x, acc[r]);
            acc[r] = fmaf(xv.y, wv.y, acc[r]);
            acc[r] = fmaf(xv.z, wv.z, acc[r]);
            acc[r] = fmaf(xv.w, wv.w, acc[r]);
        }
    }
#pragma unroll
    for (int r = 0; r < 16; ++r) {
        int row = r0 + r;
        if (row < n) hs1[(size_t)row * 64 + ch] = dis[row] * acc[r];
    }
}

// pull + relu: hs2[i] = dis[i]*relu(dis[i]*(hs1[i]+sum_neigh)+b1)
__global__ __launch_bounds__(256) void k_pull1(const int* __restrict__ rowptr,
                                               const int* __restrict__ csr,
                                               const float* __restrict__ hs1,
                                               const float* __restrict__ dis,
                                               const float* __restrict__ b1,
                                               float* __restrict__ hs2, int n) {
    int node = blockIdx.x * 16 + (threadIdx.x >> 4);
    int c4 = threadIdx.x & 15;
    if (node >= n) return;
    const float4* h4 = (const float4*)hs1;
    int beg = rowptr[node], end = rowptr[node + 1];
    float4 a0 = h4[(size_t)node * 16 + c4];
    float4 a1 = make_float4(0, 0, 0, 0), a2 = a1, a3 = a1;
    int k = beg;
    for (; k + 4 <= end; k += 4) {
        int s0 = csr[k], s1 = csr[k + 1], s2 = csr[k + 2], s3 = csr[k + 3];
        a0 = f4add(a0, h4[(size_t)s0 * 16 + c4]);
        a1 = f4add(a1, h4[(size_t)s1 * 16 + c4]);
        a2 = f4add(a2, h4[(size_t)s2 * 16 + c4]);
        a3 = f4add(a3, h4[(size_t)s3 * 16 + c4]);
    }
    for (; k < end; ++k) a0 = f4add(a0, h4[(size_t)csr[k] * 16 + c4]);
    float4 sum = f4add(f4add(a0, a1), f4add(a2, a3));
    float d = dis[node];
    float4 bb = ((const float4*)b1)[c4];
    float4 o;
    o.x = fmaf(d, sum.x, bb.x); o.x = o.x > 0.f ? d * o.x : 0.f;
    o.y = fmaf(d, sum.y, bb.y); o.y = o.y > 0.f ? d * o.y : 0.f;
    o.z = fmaf(d, sum.z, bb.z); o.z = o.z > 0.f ? d * o.z : 0.f;
    o.w = fmaf(d, sum.w, bb.w); o.w = o.w > 0.f ? d * o.w : 0.f;
    ((float4*)hs2)[(size_t)node * 16 + c4] = o;
}

// pull: gagg[i] = dis[i]*(hs2[i]+sum_neigh)
__global__ __launch_bounds__(256) void k_pull2(const int* __restrict__ rowptr,
                                               const int* __restrict__ csr,
                                               const float* __restrict__ hs2,
                                               const float* __restrict__ dis,
                                               float* __restrict__ gagg, int n) {
    int node = blockIdx.x * 16 + (threadIdx.x >> 4);
    int c4 = threadIdx.x & 15;
    if (node >= n) return;
    const float4* h4 = (const float4*)hs2;
    int beg = rowptr[node], end = rowptr[node + 1];
    float4 a0 = h4[(size_t)node * 16 + c4];
    float4 a1 = make_float4(0, 0, 0, 0), a2 = a1, a3 = a1;
    int k = beg;
    for (; k + 4 <= end; k += 4) {
        int s0 = csr[k], s1 = csr[k + 1], s2 = csr[k + 2], s3 = csr[k + 3];
        a0 = f4add(a0, h4[(size_t)s0 * 16 + c4]);
        a1 = f4add(a1, h4[(size_t)s1 * 16 + c4]);
        a2 = f4add(a2, h4[(size_t)s2 * 16 + c4]);
        a3 = f4add(a3, h4[(size_t)s3 * 16 + c4]);
    }
    for (; k < end; ++k) a0 = f4add(a0, h4[(size_t)csr[k] * 16 + c4]);
    float4 sum = f4add(f4add(a0, a1), f4add(a2, a3));
    float d = dis[node];
    ((float4*)gagg)[(size_t)node * 16 + c4] =
        make_float4(d * sum.x, d * sum.y, d * sum.z, d * sum.w);
}

// g[n,64] @ {W2,W3}[64,32] + bias -> out = mu ++ logvar. 64 rows/block.
// Wave: 16 rows; half-wave 0 -> W2/mu, half-wave 1 -> W3/logvar.
__global__ __launch_bounds__(256) void k_gemm23(const float* __restrict__ g,
                                                const float* __restrict__ W2,
                                                const float* __restrict__ b2,
                                                const float* __restrict__ W3,
                                                const float* __restrict__ b3,
                                                float* __restrict__ out, int n) {
    __shared__ float ws[2 * 32 * 17 * 4];  // [half][ch][k4] float4, stride 17
    __shared__ float4 gs[4][16 * 16];      // per-wave 16 rows x 16 float4
    for (int i = threadIdx.x; i < 64 * 32; i += 256) {
        int k = i >> 5, c = i & 31;
        int a = (c * 17 + (k >> 2)) * 4 + (k & 3);
        ws[a] = W2[i];
        ws[2176 + a] = W3[i];
    }
    int wid = threadIdx.x >> 6;
    int lane = threadIdx.x & 63;
    int half = lane >> 5;
    int ch = lane & 31;
    int r0 = blockIdx.x * 64 + wid * 16;
    const float4* g4 = (const float4*)g;
#pragma unroll
    for (int j = 0; j < 4; ++j) {
        int idx = j * 64 + lane;           // 0..255: (row, k4) = (idx>>4, idx&15)
        int rr = r0 + (idx >> 4);
        if (rr >= n) rr = n - 1;
        gs[wid][idx] = g4[(size_t)rr * 16 + (idx & 15)];
    }
    __syncthreads();
    float acc[16];
#pragma unroll
    for (int r = 0; r < 16; ++r) acc[r] = 0.f;
    const float4* wl = (const float4*)ws;
    const float4* gw = gs[wid];
#pragma unroll
    for (int k4 = 0; k4 < 16; ++k4) {
        float4 wv = wl[half * 544 + ch * 17 + k4];
#pragma unroll
        for (int r = 0; r < 16; ++r) {
            float4 gv = gw[r * 16 + k4];   // wave-uniform -> LDS broadcast
            acc[r] = fmaf(gv.x, wv.x, acc[r]);
            acc[r] = fmaf(gv.y, wv.y, acc[r]);
            acc[r] = fmaf(gv.z, wv.z, acc[r]);
            acc[r] = fmaf(gv.w, wv.w, acc[r]);
        }
    }
    float bb = half ? b3[ch] : b2[ch];
    size_t obase = half ? (size_t)n * 32 : 0;
#pragma unroll
    for (int r = 0; r < 16; ++r) {
        int row = r0 + r;
        if (row < n) out[obase + (size_t)row * 32 + ch] = acc[r] + bb;
    }
}

extern "C" void kernel_launch(void* const* d_in, const int* in_sizes, int n_in,
                              void* d_out, int out_size, void* d_ws, size_t ws_size,
                              hipStream_t stream) {
    const float* x  = (const float*)d_in[0];
    const int*   ei = (const int*)d_in[1];
    const float* W1 = (const float*)d_in[2];
    const float* b1 = (const float*)d_in[3];
    const float* W2 = (const float*)d_in[4];
    const float* b2 = (const float*)d_in[5];
    const float* W3 = (const float*)d_in[6];
    const float* b3 = (const float*)d_in[7];

    int n = in_sizes[0] / 128;   // 50000
    int e = in_sizes[1] / 2;     // 1600000
    int nb = (n + 255) >> 8;     // 196 coarse buckets
    const int* row = ei;
    const int* col = ei + e;

    float* fws  = (float*)d_ws;
    float* dis  = fws;                        // n
    float* hs1  = fws + n;                    // n*64
    float* hs2  = hs1 + (size_t)n * 64;       // n*64
    float* gagg = hs1;                        // alias: hs1 dead after pull1
    int* binbuf = (int*)hs1;                  // e ints, dead before gemm1
    int* cnt    = (int*)(hs2 + (size_t)n * 64);
    int* bbase  = cnt + nb;
    int* bcur   = bbase + nb + 1;
    int* rowptr = bcur + nb;
    int* csr    = rowptr + n + 1;
    float* out  = (float*)d_out;

    int chunk = (e + nb - 1) / nb;

    dim3 blk(256);
    hipMemsetAsync(cnt, 0, (size_t)nb * 4, stream);
    k_hist<<<nb, blk, 0, stream>>>(col, cnt, e);
    k_scanb<<<1, blk, 0, stream>>>(cnt, bbase, bcur, rowptr, nb, n, e);
    k_tilesort<<<nb, blk, 0, stream>>>(row, col, bcur, binbuf, e, chunk);
    k_build<<<nb, blk, 0, stream>>>(binbuf, bbase, dis, rowptr, csr, n);

    k_gemm1<<<(n + 63) / 64, blk, 0, stream>>>(x, W1, dis, hs1, n);
    k_pull1<<<(n + 15) / 16, blk, 0, stream>>>(rowptr, csr, hs1, dis, b1, hs2, n);
    k_pull2<<<(n + 15) / 16, blk, 0, stream>>>(rowptr, csr, hs2, dis, gagg, n);
    k_gemm23<<<(n + 63) / 64, blk, 0, stream>>>(gagg, W2, b2, W3, b3, out, n);
}

// Round 8
// 269.191 us; speedup vs baseline: 1.9074x; 1.9074x over previous
//
#include <hip/hip_runtime.h>

// GCN VGAE encoder, pull-based. N=50000 (<2^16: rows pack in 16 bits), E=1.6M.
// out[i] = dis[i] * (hs[i] + sum_{j->i} hs[j]),  hs = dis .* (x@W)
// CSR build: coarse-bucket (256 nodes) counting sort with XCD-clean writes.
// GEMMs: per-wave row-tile staged in LDS (coalesced load, broadcast read).
// NOTE: k4 loops use bounded unroll (2/4) — full unroll spilled to scratch
// (VGPR=256, 467MB scratch writes, 261us) in round 7.

#define NBMAX 256

__device__ __forceinline__ float4 f4add(float4 a, float4 b) {
    return make_float4(a.x + b.x, a.y + b.y, a.z + b.z, a.w + b.w);
}

__global__ __launch_bounds__(256) void k_hist(const int* __restrict__ col,
                                              int* __restrict__ bcnt, int e) {
    __shared__ int h[NBMAX];
    for (int i = threadIdx.x; i < NBMAX; i += 256) h[i] = 0;
    __syncthreads();
    for (int i = blockIdx.x * 256 + threadIdx.x; i < e; i += gridDim.x * 256)
        atomicAdd(&h[col[i] >> 8], 1);
    __syncthreads();
    for (int i = threadIdx.x; i < NBMAX; i += 256)
        if (h[i]) atomicAdd(bcnt + i, h[i]);
}

__global__ __launch_bounds__(256) void k_scanb(const int* __restrict__ bcnt,
                                               int* __restrict__ bbase,
                                               int* __restrict__ bcur,
                                               int* __restrict__ rowptr,
                                               int nb, int n, int e) {
    __shared__ int s[256];
    int t = threadIdx.x;
    int v = (t < nb) ? bcnt[t] : 0;
    s[t] = v;
    __syncthreads();
    for (int off = 1; off < 256; off <<= 1) {
        int u = (t >= off) ? s[t - off] : 0;
        __syncthreads();
        s[t] += u;
        __syncthreads();
    }
    int excl = s[t] - v;
    if (t <= nb) bbase[t] = (t < nb) ? excl : e;
    if (t < nb) bcur[t] = excl;
    if (t == 0) rowptr[n] = e;
}

__global__ __launch_bounds__(256) void k_tilesort(const int* __restrict__ row,
                                                  const int* __restrict__ col,
                                                  int* __restrict__ bcur,
                                                  int* __restrict__ binbuf,
                                                  int e, int chunk) {
    __shared__ int lh[NBMAX];
    int t0 = blockIdx.x * chunk;
    int t1 = t0 + chunk < e ? t0 + chunk : e;
    for (int i = threadIdx.x; i < NBMAX; i += 256) lh[i] = 0;
    __syncthreads();
    for (int i = t0 + threadIdx.x; i < t1; i += 256)
        atomicAdd(&lh[col[i] >> 8], 1);
    __syncthreads();
    for (int b = threadIdx.x; b < NBMAX; b += 256) {
        int c = lh[b];
        if (c) lh[b] = atomicAdd(bcur + b, c);
    }
    __syncthreads();
    for (int i = t0 + threadIdx.x; i < t1; i += 256) {
        int c = col[i];
        int pos = atomicAdd(&lh[c >> 8], 1);
        binbuf[pos] = row[i] | ((c & 255) << 16);
    }
}

__global__ __launch_bounds__(256) void k_build(const int* __restrict__ binbuf,
                                               const int* __restrict__ bbase,
                                               float* __restrict__ dis,
                                               int* __restrict__ rowptr,
                                               int* __restrict__ csr, int n) {
    __shared__ int lcnt[256], s[256], cur[256];
    int b = blockIdx.x;
    int t = threadIdx.x;
    int lo = bbase[b], hi = bbase[b + 1];
    int node0 = b << 8;
    int nloc = n - node0 < 256 ? n - node0 : 256;
    lcnt[t] = 0;
    __syncthreads();
    for (int k = lo + t; k < hi; k += 256)
        atomicAdd(&lcnt[(binbuf[k] >> 16) & 255], 1);
    __syncthreads();
    int v = lcnt[t];
    s[t] = v;
    __syncthreads();
    for (int off = 1; off < 256; off <<= 1) {
        int u = (t >= off) ? s[t - off] : 0;
        __syncthreads();
        s[t] += u;
        __syncthreads();
    }
    if (t < nloc) {
        int rp = lo + s[t] - v;
        rowptr[node0 + t] = rp;
        cur[t] = rp;
        dis[node0 + t] = rsqrtf((float)v + 1.0f);
    }
    __syncthreads();
    for (int k = lo + t; k < hi; k += 256) {
        int p = binbuf[k];
        int pos = atomicAdd(&cur[(p >> 16) & 255], 1);
        csr[pos] = p & 0xffff;
    }
}

// x[n,128] @ W[128,64] * dis -> hs1[n,64]. 64 rows/block, 16 rows/wave.
__global__ __launch_bounds__(256) void k_gemm1(const float* __restrict__ x,
                                               const float* __restrict__ W,
                                               const float* __restrict__ dis,
                                               float* __restrict__ hs1, int n) {
    __shared__ float w4[64 * 33 * 4];      // W^T as float4 [ch][k4], stride 33
    __shared__ float4 xs[4][16 * 32];      // per-wave 16 rows x 32 float4
    for (int i = threadIdx.x; i < 128 * 64; i += 256) {
        int k = i >> 6, c = i & 63;
        w4[(c * 33 + (k >> 2)) * 4 + (k & 3)] = W[i];
    }
    int wid = threadIdx.x >> 6;
    int lane = threadIdx.x & 63;
    int r0 = blockIdx.x * 64 + wid * 16;
    const float4* x4 = (const float4*)x;
#pragma unroll
    for (int j = 0; j < 8; ++j) {
        int idx = j * 64 + lane;           // (row, k4) = (idx>>5, idx&31)
        int rr = r0 + (idx >> 5);
        if (rr >= n) rr = n - 1;
        xs[wid][idx] = x4[(size_t)rr * 32 + (idx & 31)];
    }
    __syncthreads();
    int ch = lane;
    float acc[16];
#pragma unroll
    for (int r = 0; r < 16; ++r) acc[r] = 0.f;
    const float4* wl = (const float4*)w4;
    const float4* xw = xs[wid];
#pragma unroll 4
    for (int k4 = 0; k4 < 32; ++k4) {
        float4 wv = wl[ch * 33 + k4];
#pragma unroll
        for (int r = 0; r < 16; ++r) {
            float4 xv = xw[r * 32 + k4];   // wave-uniform -> LDS broadcast
            acc[r] = fmaf(xv.x, wv.x, acc[r]);
            acc[r] = fmaf(xv.y, wv.y, acc[r]);
            acc[r] = fmaf(xv.z, wv.z, acc[r]);
            acc[r] = fmaf(xv.w, wv.w, acc[r]);
        }
    }
#pragma unroll
    for (int r = 0; r < 16; ++r) {
        int row = r0 + r;
        if (row < n) hs1[(size_t)row * 64 + ch] = dis[row] * acc[r];
    }
}

// pull + relu: hs2[i] = dis[i]*relu(dis[i]*(hs1[i]+sum_neigh)+b1)
__global__ __launch_bounds__(256) void k_pull1(const int* __restrict__ rowptr,
                                               const int* __restrict__ csr,
                                               const float* __restrict__ hs1,
                                               const float* __restrict__ dis,
                                               const float* __restrict__ b1,
                                               float* __restrict__ hs2, int n) {
    int node = blockIdx.x * 16 + (threadIdx.x >> 4);
    int c4 = threadIdx.x & 15;
    if (node >= n) return;
    const float4* h4 = (const float4*)hs1;
    int beg = rowptr[node], end = rowptr[node + 1];
    float4 a0 = h4[(size_t)node * 16 + c4];
    float4 a1 = make_float4(0, 0, 0, 0), a2 = a1, a3 = a1;
    int k = beg;
    for (; k + 4 <= end; k += 4) {
        int s0 = csr[k], s1 = csr[k + 1], s2 = csr[k + 2], s3 = csr[k + 3];
        a0 = f4add(a0, h4[(size_t)s0 * 16 + c4]);
        a1 = f4add(a1, h4[(size_t)s1 * 16 + c4]);
        a2 = f4add(a2, h4[(size_t)s2 * 16 + c4]);
        a3 = f4add(a3, h4[(size_t)s3 * 16 + c4]);
    }
    for (; k < end; ++k) a0 = f4add(a0, h4[(size_t)csr[k] * 16 + c4]);
    float4 sum = f4add(f4add(a0, a1), f4add(a2, a3));
    float d = dis[node];
    float4 bb = ((const float4*)b1)[c4];
    float4 o;
    o.x = fmaf(d, sum.x, bb.x); o.x = o.x > 0.f ? d * o.x : 0.f;
    o.y = fmaf(d, sum.y, bb.y); o.y = o.y > 0.f ? d * o.y : 0.f;
    o.z = fmaf(d, sum.z, bb.z); o.z = o.z > 0.f ? d * o.z : 0.f;
    o.w = fmaf(d, sum.w, bb.w); o.w = o.w > 0.f ? d * o.w : 0.f;
    ((float4*)hs2)[(size_t)node * 16 + c4] = o;
}

// pull: gagg[i] = dis[i]*(hs2[i]+sum_neigh)
__global__ __launch_bounds__(256) void k_pull2(const int* __restrict__ rowptr,
                                               const int* __restrict__ csr,
                                               const float* __restrict__ hs2,
                                               const float* __restrict__ dis,
                                               float* __restrict__ gagg, int n) {
    int node = blockIdx.x * 16 + (threadIdx.x >> 4);
    int c4 = threadIdx.x & 15;
    if (node >= n) return;
    const float4* h4 = (const float4*)hs2;
    int beg = rowptr[node], end = rowptr[node + 1];
    float4 a0 = h4[(size_t)node * 16 + c4];
    float4 a1 = make_float4(0, 0, 0, 0), a2 = a1, a3 = a1;
    int k = beg;
    for (; k + 4 <= end; k += 4) {
        int s0 = csr[k], s1 = csr[k + 1], s2 = csr[k + 2], s3 = csr[k + 3];
        a0 = f4add(a0, h4[(size_t)s0 * 16 + c4]);
        a1 = f4add(a1, h4[(size_t)s1 * 16 + c4]);
        a2 = f4add(a2, h4[(size_t)s2 * 16 + c4]);
        a3 = f4add(a3, h4[(size_t)s3 * 16 + c4]);
    }
    for (; k < end; ++k) a0 = f4add(a0, h4[(size_t)csr[k] * 16 + c4]);
    float4 sum = f4add(f4add(a0, a1), f4add(a2, a3));
    float d = dis[node];
    ((float4*)gagg)[(size_t)node * 16 + c4] =
        make_float4(d * sum.x, d * sum.y, d * sum.z, d * sum.w);
}

// g[n,64] @ {W2,W3}[64,32] + bias -> out = mu ++ logvar. 64 rows/block.
// Wave: 16 rows; half-wave 0 -> W2/mu, half-wave 1 -> W3/logvar.
__global__ __launch_bounds__(256) void k_gemm23(const float* __restrict__ g,
                                                const float* __restrict__ W2,
                                                const float* __restrict__ b2,
                                                const float* __restrict__ W3,
                                                const float* __restrict__ b3,
                                                float* __restrict__ out, int n) {
    __shared__ float ws[2 * 32 * 17 * 4];  // [half][ch][k4] float4, stride 17
    __shared__ float4 gs[4][16 * 16];      // per-wave 16 rows x 16 float4
    for (int i = threadIdx.x; i < 64 * 32; i += 256) {
        int k = i >> 5, c = i & 31;
        int a = (c * 17 + (k >> 2)) * 4 + (k & 3);
        ws[a] = W2[i];
        ws[2176 + a] = W3[i];
    }
    int wid = threadIdx.x >> 6;
    int lane = threadIdx.x & 63;
    int half = lane >> 5;
    int ch = lane & 31;
    int r0 = blockIdx.x * 64 + wid * 16;
    const float4* g4 = (const float4*)g;
#pragma unroll
    for (int j = 0; j < 4; ++j) {
        int idx = j * 64 + lane;           // (row, k4) = (idx>>4, idx&15)
        int rr = r0 + (idx >> 4);
        if (rr >= n) rr = n - 1;
        gs[wid][idx] = g4[(size_t)rr * 16 + (idx & 15)];
    }
    __syncthreads();
    float acc[16];
#pragma unroll
    for (int r = 0; r < 16; ++r) acc[r] = 0.f;
    const float4* wl = (const float4*)ws;
    const float4* gw = gs[wid];
#pragma unroll 2
    for (int k4 = 0; k4 < 16; ++k4) {
        float4 wv = wl[half * 544 + ch * 17 + k4];
#pragma unroll
        for (int r = 0; r < 16; ++r) {
            float4 gv = gw[r * 16 + k4];   // wave-uniform -> LDS broadcast
            acc[r] = fmaf(gv.x, wv.x, acc[r]);
            acc[r] = fmaf(gv.y, wv.y, acc[r]);
            acc[r] = fmaf(gv.z, wv.z, acc[r]);
            acc[r] = fmaf(gv.w, wv.w, acc[r]);
        }
    }
    float bb = half ? b3[ch] : b2[ch];
    size_t obase = half ? (size_t)n * 32 : 0;
#pragma unroll
    for (int r = 0; r < 16; ++r) {
        int row = r0 + r;
        if (row < n) out[obase + (size_t)row * 32 + ch] = acc[r] + bb;
    }
}

extern "C" void kernel_launch(void* const* d_in, const int* in_sizes, int n_in,
                              void* d_out, int out_size, void* d_ws, size_t ws_size,
                              hipStream_t stream) {
    const float* x  = (const float*)d_in[0];
    const int*   ei = (const int*)d_in[1];
    const float* W1 = (const float*)d_in[2];
    const float* b1 = (const float*)d_in[3];
    const float* W2 = (const float*)d_in[4];
    const float* b2 = (const float*)d_in[5];
    const float* W3 = (const float*)d_in[6];
    const float* b3 = (const float*)d_in[7];

    int n = in_sizes[0] / 128;   // 50000
    int e = in_sizes[1] / 2;     // 1600000
    int nb = (n + 255) >> 8;     // 196 coarse buckets
    const int* row = ei;
    const int* col = ei + e;

    float* fws  = (float*)d_ws;
    float* dis  = fws;                        // n
    float* hs1  = fws + n;                    // n*64
    float* hs2  = hs1 + (size_t)n * 64;       // n*64
    float* gagg = hs1;                        // alias: hs1 dead after pull1
    int* binbuf = (int*)hs1;                  // e ints, dead before gemm1
    int* cnt    = (int*)(hs2 + (size_t)n * 64);
    int* bbase  = cnt + nb;
    int* bcur   = bbase + nb + 1;
    int* rowptr = bcur + nb;
    int* csr    = rowptr + n + 1;
    float* out  = (float*)d_out;

    int chunk = (e + nb - 1) / nb;

    dim3 blk(256);
    hipMemsetAsync(cnt, 0, (size_t)nb * 4, stream);
    k_hist<<<nb, blk, 0, stream>>>(col, cnt, e);
    k_scanb<<<1, blk, 0, stream>>>(cnt, bbase, bcur, rowptr, nb, n, e);
    k_tilesort<<<nb, blk, 0, stream>>>(row, col, bcur, binbuf, e, chunk);
    k_build<<<nb, blk, 0, stream>>>(binbuf, bbase, dis, rowptr, csr, n);

    k_gemm1<<<(n + 63) / 64, blk, 0, stream>>>(x, W1, dis, hs1, n);
    k_pull1<<<(n + 15) / 16, blk, 0, stream>>>(rowptr, csr, hs1, dis, b1, hs2, n);
    k_pull2<<<(n + 15) / 16, blk, 0, stream>>>(rowptr, csr, hs2, dis, gagg, n);
    k_gemm23<<<(n + 63) / 64, blk, 0, stream>>>(gagg, W2, b2, W3, b3, out, n);
}

// Round 9
// 201.141 us; speedup vs baseline: 2.5528x; 1.3383x over previous
//
#include <hip/hip_runtime.h>

// GCN VGAE encoder, pull-based. N=50000 (<2^16: ids pack in 16 bits), E=1.6M.
// out[i] = dis[i] * (hs[i] + sum_{j->i} hs[j]),  hs = dis .* (x@W)
// CSR build: coarse-bucket (256 nodes) counting sort, XCD-clean writes.
// Pulls: bf16 operand slabs of 32 ch (3.2 MB) so each pass's gather source is
// per-XCD-L2-resident (round 8: fp32 12.8MB source -> 221MB L2-miss fetch).
// NOTE: k4 loops use bounded unroll — full unroll spilled (round 7: VGPR=256).

#define NBMAX 256

__device__ __forceinline__ ushort f2bf(float x) {            // RNE fp32->bf16
    unsigned u = __float_as_uint(x);
    u = (u + 0x7FFFu + ((u >> 16) & 1u)) >> 16;
    return (ushort)u;
}
__device__ __forceinline__ float bflo(unsigned u) { return __uint_as_float(u << 16); }
__device__ __forceinline__ float bfhi(unsigned u) { return __uint_as_float(u & 0xFFFF0000u); }

__device__ __forceinline__ void acc8(float* a, uint4 x) {    // a[0..7] += 8 bf16
    a[0] += bflo(x.x); a[1] += bfhi(x.x);
    a[2] += bflo(x.y); a[3] += bfhi(x.y);
    a[4] += bflo(x.z); a[5] += bfhi(x.z);
    a[6] += bflo(x.w); a[7] += bfhi(x.w);
}

__global__ __launch_bounds__(256) void k_hist(const int* __restrict__ col,
                                              int* __restrict__ bcnt, int e) {
    __shared__ int h[NBMAX];
    for (int i = threadIdx.x; i < NBMAX; i += 256) h[i] = 0;
    __syncthreads();
    for (int i = blockIdx.x * 256 + threadIdx.x; i < e; i += gridDim.x * 256)
        atomicAdd(&h[col[i] >> 8], 1);
    __syncthreads();
    for (int i = threadIdx.x; i < NBMAX; i += 256)
        if (h[i]) atomicAdd(bcnt + i, h[i]);
}

__global__ __launch_bounds__(256) void k_scanb(const int* __restrict__ bcnt,
                                               int* __restrict__ bbase,
                                               int* __restrict__ bcur,
                                               int* __restrict__ rowptr,
                                               int nb, int n, int e) {
    __shared__ int s[256];
    int t = threadIdx.x;
    int v = (t < nb) ? bcnt[t] : 0;
    s[t] = v;
    __syncthreads();
    for (int off = 1; off < 256; off <<= 1) {
        int u = (t >= off) ? s[t - off] : 0;
        __syncthreads();
        s[t] += u;
        __syncthreads();
    }
    int excl = s[t] - v;
    if (t <= nb) bbase[t] = (t < nb) ? excl : e;
    if (t < nb) bcur[t] = excl;
    if (t == 0) rowptr[n] = e;
}

__global__ __launch_bounds__(256) void k_tilesort(const int* __restrict__ row,
                                                  const int* __restrict__ col,
                                                  int* __restrict__ bcur,
                                                  int* __restrict__ binbuf,
                                                  int e, int chunk) {
    __shared__ int lh[NBMAX];
    int t0 = blockIdx.x * chunk;
    int t1 = t0 + chunk < e ? t0 + chunk : e;
    for (int i = threadIdx.x; i < NBMAX; i += 256) lh[i] = 0;
    __syncthreads();
    for (int i = t0 + threadIdx.x; i < t1; i += 256)
        atomicAdd(&lh[col[i] >> 8], 1);
    __syncthreads();
    for (int b = threadIdx.x; b < NBMAX; b += 256) {
        int c = lh[b];
        if (c) lh[b] = atomicAdd(bcur + b, c);
    }
    __syncthreads();
    for (int i = t0 + threadIdx.x; i < t1; i += 256) {
        int c = col[i];
        int pos = atomicAdd(&lh[c >> 8], 1);
        binbuf[pos] = row[i] | ((c & 255) << 16);
    }
}

__global__ __launch_bounds__(256) void k_build(const int* __restrict__ binbuf,
                                               const int* __restrict__ bbase,
                                               float* __restrict__ dis,
                                               int* __restrict__ rowptr,
                                               ushort* __restrict__ csr, int n) {
    __shared__ int lcnt[256], s[256], cur[256];
    int b = blockIdx.x;
    int t = threadIdx.x;
    int lo = bbase[b], hi = bbase[b + 1];
    int node0 = b << 8;
    int nloc = n - node0 < 256 ? n - node0 : 256;
    lcnt[t] = 0;
    __syncthreads();
    for (int k = lo + t; k < hi; k += 256)
        atomicAdd(&lcnt[(binbuf[k] >> 16) & 255], 1);
    __syncthreads();
    int v = lcnt[t];
    s[t] = v;
    __syncthreads();
    for (int off = 1; off < 256; off <<= 1) {
        int u = (t >= off) ? s[t - off] : 0;
        __syncthreads();
        s[t] += u;
        __syncthreads();
    }
    if (t < nloc) {
        int rp = lo + s[t] - v;
        rowptr[node0 + t] = rp;
        cur[t] = rp;
        dis[node0 + t] = rsqrtf((float)v + 1.0f);
    }
    __syncthreads();
    for (int k = lo + t; k < hi; k += 256) {
        int p = binbuf[k];
        int pos = atomicAdd(&cur[(p >> 16) & 255], 1);
        csr[pos] = (ushort)(p & 0xffff);
    }
}

// x[n,128] @ W[128,64] * dis -> bf16 slabs hs1b[2][n][32]. 64 rows/block.
__global__ __launch_bounds__(256) void k_gemm1(const float* __restrict__ x,
                                               const float* __restrict__ W,
                                               const float* __restrict__ dis,
                                               ushort* __restrict__ hs1b, int n) {
    __shared__ float w4[64 * 33 * 4];      // W^T as float4 [ch][k4], stride 33
    __shared__ float4 xs[4][16 * 32];      // per-wave 16 rows x 32 float4
    for (int i = threadIdx.x; i < 128 * 64; i += 256) {
        int k = i >> 6, c = i & 63;
        w4[(c * 33 + (k >> 2)) * 4 + (k & 3)] = W[i];
    }
    int wid = threadIdx.x >> 6;
    int lane = threadIdx.x & 63;
    int r0 = blockIdx.x * 64 + wid * 16;
    const float4* x4 = (const float4*)x;
#pragma unroll
    for (int j = 0; j < 8; ++j) {
        int idx = j * 64 + lane;           // (row, k4) = (idx>>5, idx&31)
        int rr = r0 + (idx >> 5);
        if (rr >= n) rr = n - 1;
        xs[wid][idx] = x4[(size_t)rr * 32 + (idx & 31)];
    }
    __syncthreads();
    int ch = lane;
    float acc[16];
#pragma unroll
    for (int r = 0; r < 16; ++r) acc[r] = 0.f;
    const float4* wl = (const float4*)w4;
    const float4* xw = xs[wid];
#pragma unroll 4
    for (int k4 = 0; k4 < 32; ++k4) {
        float4 wv = wl[ch * 33 + k4];
#pragma unroll
        for (int r = 0; r < 16; ++r) {
            float4 xv = xw[r * 32 + k4];   // wave-uniform -> LDS broadcast
            acc[r] = fmaf(xv.x, wv.x, acc[r]);
            acc[r] = fmaf(xv.y, wv.y, acc[r]);
            acc[r] = fmaf(xv.z, wv.z, acc[r]);
            acc[r] = fmaf(xv.w, wv.w, acc[r]);
        }
    }
    ushort* hb = hs1b + (size_t)(ch >> 5) * n * 32 + (ch & 31);
#pragma unroll
    for (int r = 0; r < 16; ++r) {
        int row = r0 + r;
        if (row < n) hb[(size_t)row * 32] = f2bf(dis[row] * acc[r]);
    }
}

// pull1 over one 32-ch bf16 slab: ob = bf16(dis*relu(dis*(self+sum)+b1s))
// 4 lanes/node, uint4 (8 bf16) per lane; per edge: one 64B line.
__global__ __launch_bounds__(256) void k_pull1(const int* __restrict__ rowptr,
                                               const ushort* __restrict__ csr,
                                               const ushort* __restrict__ hb,
                                               const float* __restrict__ dis,
                                               const float* __restrict__ b1s,
                                               ushort* __restrict__ ob, int n) {
    int node = blockIdx.x * 64 + (threadIdx.x >> 2);
    int c4 = threadIdx.x & 3;
    if (node >= n) return;
    const uint4* h4 = (const uint4*)hb;
    int beg = rowptr[node], end = rowptr[node + 1];
    float a[8], b[8];
    uint4 v = h4[(size_t)node * 4 + c4];
    a[0] = bflo(v.x); a[1] = bfhi(v.x); a[2] = bflo(v.y); a[3] = bfhi(v.y);
    a[4] = bflo(v.z); a[5] = bfhi(v.z); a[6] = bflo(v.w); a[7] = bfhi(v.w);
#pragma unroll
    for (int j = 0; j < 8; ++j) b[j] = 0.f;
    int k = beg;
    for (; k + 4 <= end; k += 4) {
        uint4 v0 = h4[(size_t)csr[k] * 4 + c4];
        uint4 v1 = h4[(size_t)csr[k + 1] * 4 + c4];
        uint4 v2 = h4[(size_t)csr[k + 2] * 4 + c4];
        uint4 v3 = h4[(size_t)csr[k + 3] * 4 + c4];
        acc8(a, v0); acc8(b, v1); acc8(a, v2); acc8(b, v3);
    }
    for (; k < end; ++k) acc8(a, h4[(size_t)csr[k] * 4 + c4]);
    float d = dis[node];
    float4 bb0 = *(const float4*)(b1s + c4 * 8);
    float4 bb1 = *(const float4*)(b1s + c4 * 8 + 4);
    float bj[8] = {bb0.x, bb0.y, bb0.z, bb0.w, bb1.x, bb1.y, bb1.z, bb1.w};
    float o[8];
#pragma unroll
    for (int j = 0; j < 8; ++j) {
        float t = fmaf(d, a[j] + b[j], bj[j]);
        o[j] = t > 0.f ? d * t : 0.f;
    }
    uint4 w;
    w.x = (unsigned)f2bf(o[0]) | ((unsigned)f2bf(o[1]) << 16);
    w.y = (unsigned)f2bf(o[2]) | ((unsigned)f2bf(o[3]) << 16);
    w.z = (unsigned)f2bf(o[4]) | ((unsigned)f2bf(o[5]) << 16);
    w.w = (unsigned)f2bf(o[6]) | ((unsigned)f2bf(o[7]) << 16);
    ((uint4*)ob)[(size_t)node * 4 + c4] = w;
}

// pull2 over one slab: og[node*64 + c] = dis*(self+sum), fp32 out for gemm23
__global__ __launch_bounds__(256) void k_pull2(const int* __restrict__ rowptr,
                                               const ushort* __restrict__ csr,
                                               const ushort* __restrict__ hb,
                                               const float* __restrict__ dis,
                                               float* __restrict__ og, int n) {
    int node = blockIdx.x * 64 + (threadIdx.x >> 2);
    int c4 = threadIdx.x & 3;
    if (node >= n) return;
    const uint4* h4 = (const uint4*)hb;
    int beg = rowptr[node], end = rowptr[node + 1];
    float a[8], b[8];
    uint4 v = h4[(size_t)node * 4 + c4];
    a[0] = bflo(v.x); a[1] = bfhi(v.x); a[2] = bflo(v.y); a[3] = bfhi(v.y);
    a[4] = bflo(v.z); a[5] = bfhi(v.z); a[6] = bflo(v.w); a[7] = bfhi(v.w);
#pragma unroll
    for (int j = 0; j < 8; ++j) b[j] = 0.f;
    int k = beg;
    for (; k + 4 <= end; k += 4) {
        uint4 v0 = h4[(size_t)csr[k] * 4 + c4];
        uint4 v1 = h4[(size_t)csr[k + 1] * 4 + c4];
        uint4 v2 = h4[(size_t)csr[k + 2] * 4 + c4];
        uint4 v3 = h4[(size_t)csr[k + 3] * 4 + c4];
        acc8(a, v0); acc8(b, v1); acc8(a, v2); acc8(b, v3);
    }
    for (; k < end; ++k) acc8(a, h4[(size_t)csr[k] * 4 + c4]);
    float d = dis[node];
    float* dst = og + (size_t)node * 64 + c4 * 8;
    *(float4*)dst = make_float4(d * (a[0] + b[0]), d * (a[1] + b[1]),
                                d * (a[2] + b[2]), d * (a[3] + b[3]));
    *(float4*)(dst + 4) = make_float4(d * (a[4] + b[4]), d * (a[5] + b[5]),
                                      d * (a[6] + b[6]), d * (a[7] + b[7]));
}

// g[n,64] @ {W2,W3}[64,32] + bias -> out = mu ++ logvar. 64 rows/block.
__global__ __launch_bounds__(256) void k_gemm23(const float* __restrict__ g,
                                                const float* __restrict__ W2,
                                                const float* __restrict__ b2,
                                                const float* __restrict__ W3,
                                                const float* __restrict__ b3,
                                                float* __restrict__ out, int n) {
    __shared__ float ws[2 * 32 * 17 * 4];  // [half][ch][k4] float4, stride 17
    __shared__ float4 gs[4][16 * 16];      // per-wave 16 rows x 16 float4
    for (int i = threadIdx.x; i < 64 * 32; i += 256) {
        int k = i >> 5, c = i & 31;
        int a = (c * 17 + (k >> 2)) * 4 + (k & 3);
        ws[a] = W2[i];
        ws[2176 + a] = W3[i];
    }
    int wid = threadIdx.x >> 6;
    int lane = threadIdx.x & 63;
    int half = lane >> 5;
    int ch = lane & 31;
    int r0 = blockIdx.x * 64 + wid * 16;
    const float4* g4 = (const float4*)g;
#pragma unroll
    for (int j = 0; j < 4; ++j) {
        int idx = j * 64 + lane;           // (row, k4) = (idx>>4, idx&15)
        int rr = r0 + (idx >> 4);
        if (rr >= n) rr = n - 1;
        gs[wid][idx] = g4[(size_t)rr * 16 + (idx & 15)];
    }
    __syncthreads();
    float acc[16];
#pragma unroll
    for (int r = 0; r < 16; ++r) acc[r] = 0.f;
    const float4* wl = (const float4*)ws;
    const float4* gw = gs[wid];
#pragma unroll 2
    for (int k4 = 0; k4 < 16; ++k4) {
        float4 wv = wl[half * 544 + ch * 17 + k4];
#pragma unroll
        for (int r = 0; r < 16; ++r) {
            float4 gv = gw[r * 16 + k4];   // wave-uniform -> LDS broadcast
            acc[r] = fmaf(gv.x, wv.x, acc[r]);
            acc[r] = fmaf(gv.y, wv.y, acc[r]);
            acc[r] = fmaf(gv.z, wv.z, acc[r]);
            acc[r] = fmaf(gv.w, wv.w, acc[r]);
        }
    }
    float bb = half ? b3[ch] : b2[ch];
    size_t obase = half ? (size_t)n * 32 : 0;
#pragma unroll
    for (int r = 0; r < 16; ++r) {
        int row = r0 + r;
        if (row < n) out[obase + (size_t)row * 32 + ch] = acc[r] + bb;
    }
}

extern "C" void kernel_launch(void* const* d_in, const int* in_sizes, int n_in,
                              void* d_out, int out_size, void* d_ws, size_t ws_size,
                              hipStream_t stream) {
    const float* x  = (const float*)d_in[0];
    const int*   ei = (const int*)d_in[1];
    const float* W1 = (const float*)d_in[2];
    const float* b1 = (const float*)d_in[3];
    const float* W2 = (const float*)d_in[4];
    const float* b2 = (const float*)d_in[5];
    const float* W3 = (const float*)d_in[6];
    const float* b3 = (const float*)d_in[7];

    int n = in_sizes[0] / 128;   // 50000
    int e = in_sizes[1] / 2;     // 1600000
    int nb = (n + 255) >> 8;     // 196 coarse buckets
    const int* row = ei;
    const int* col = ei + e;

    float* fws   = (float*)d_ws;
    float* dis   = fws;                                   // n fp32
    ushort* hs1b = (ushort*)(fws + n);                    // 2 slabs x n x 32 bf16
    ushort* hs2b = hs1b + (size_t)2 * n * 32;             // 2 slabs x n x 32 bf16
    float* gagg  = (float*)(hs2b + (size_t)2 * n * 32);   // n x 64 fp32
    int* binbuf  = (int*)gagg;                            // e ints (dead before pull2)
    int* cnt     = (int*)(gagg + (size_t)n * 64);         // nb
    int* bbase   = cnt + nb;                              // nb+1
    int* bcur    = bbase + nb + 1;                        // nb
    int* rowptr  = bcur + nb;                             // n+1
    ushort* csr  = (ushort*)(rowptr + n + 1);             // e ushorts
    float* out   = (float*)d_out;

    size_t ns32 = (size_t)n * 32;
    int chunk = (e + nb - 1) / nb;

    dim3 blk(256);
    hipMemsetAsync(cnt, 0, (size_t)nb * 4, stream);
    k_hist<<<nb, blk, 0, stream>>>(col, cnt, e);
    k_scanb<<<1, blk, 0, stream>>>(cnt, bbase, bcur, rowptr, nb, n, e);
    k_tilesort<<<nb, blk, 0, stream>>>(row, col, bcur, binbuf, e, chunk);
    k_build<<<nb, blk, 0, stream>>>(binbuf, bbase, dis, rowptr, csr, n);

    k_gemm1<<<(n + 63) / 64, blk, 0, stream>>>(x, W1, dis, hs1b, n);

    int pg = (n + 63) / 64;
    k_pull1<<<pg, blk, 0, stream>>>(rowptr, csr, hs1b,        dis, b1,      hs2b,        n);
    k_pull1<<<pg, blk, 0, stream>>>(rowptr, csr, hs1b + ns32, dis, b1 + 32, hs2b + ns32, n);
    k_pull2<<<pg, blk, 0, stream>>>(rowptr, csr, hs2b,        dis, gagg,      n);
    k_pull2<<<pg, blk, 0, stream>>>(rowptr, csr, hs2b + ns32, dis, gagg + 32, n);

    k_gemm23<<<(n + 63) / 64, blk, 0, stream>>>(gagg, W2, b2, W3, b3, out, n);
}

// Round 10
// 188.784 us; speedup vs baseline: 2.7199x; 1.0655x over previous
//
#include <hip/hip_runtime.h>

// GCN VGAE encoder, pull-based. N=50000 (<2^16: ids pack in 16 bits), E=1.6M.
// out[i] = dis[i] * (hs[i] + sum_{j->i} hs[j]),  hs = dis .* (x@W)
// CSR build: coarse-bucket (256 nodes) counting sort, XCD-clean writes;
// tilesort uses 512 tiles (run length ~16 = one 64B line) for occupancy.
// Pulls: bf16 slabs of 32 ch (3.2 MB) -> per-XCD-L2-resident gather source.
// gemm1: W as [k4][ch] (32KB, conflict-free), x staged in 4 K-stages (8KB)
// -> 40KB LDS = 4 blocks/CU. Bounded unrolls (round 7: full unroll spilled).

#define NBMAX 256
#define NTILE 512

__device__ __forceinline__ ushort f2bf(float x) {            // RNE fp32->bf16
    unsigned u = __float_as_uint(x);
    u = (u + 0x7FFFu + ((u >> 16) & 1u)) >> 16;
    return (ushort)u;
}
__device__ __forceinline__ float bflo(unsigned u) { return __uint_as_float(u << 16); }
__device__ __forceinline__ float bfhi(unsigned u) { return __uint_as_float(u & 0xFFFF0000u); }

__device__ __forceinline__ void acc8(float* a, uint4 x) {    // a[0..7] += 8 bf16
    a[0] += bflo(x.x); a[1] += bfhi(x.x);
    a[2] += bflo(x.y); a[3] += bfhi(x.y);
    a[4] += bflo(x.z); a[5] += bfhi(x.z);
    a[6] += bflo(x.w); a[7] += bfhi(x.w);
}

__global__ __launch_bounds__(256) void k_hist(const int* __restrict__ col,
                                              int* __restrict__ bcnt, int e) {
    __shared__ int h[NBMAX];
    for (int i = threadIdx.x; i < NBMAX; i += 256) h[i] = 0;
    __syncthreads();
    for (int i = blockIdx.x * 256 + threadIdx.x; i < e; i += gridDim.x * 256)
        atomicAdd(&h[col[i] >> 8], 1);
    __syncthreads();
    for (int i = threadIdx.x; i < NBMAX; i += 256)
        if (h[i]) atomicAdd(bcnt + i, h[i]);
}

__global__ __launch_bounds__(256) void k_scanb(const int* __restrict__ bcnt,
                                               int* __restrict__ bbase,
                                               int* __restrict__ bcur,
                                               int* __restrict__ rowptr,
                                               int nb, int n, int e) {
    __shared__ int s[256];
    int t = threadIdx.x;
    int v = (t < nb) ? bcnt[t] : 0;
    s[t] = v;
    __syncthreads();
    for (int off = 1; off < 256; off <<= 1) {
        int u = (t >= off) ? s[t - off] : 0;
        __syncthreads();
        s[t] += u;
        __syncthreads();
    }
    int excl = s[t] - v;
    if (t <= nb) bbase[t] = (t < nb) ? excl : e;
    if (t < nb) bcur[t] = excl;
    if (t == 0) rowptr[n] = e;
}

__global__ __launch_bounds__(256) void k_tilesort(const int* __restrict__ row,
                                                  const int* __restrict__ col,
                                                  int* __restrict__ bcur,
                                                  int* __restrict__ binbuf,
                                                  int e, int chunk) {
    __shared__ int lh[NBMAX];
    int t0 = blockIdx.x * chunk;
    int t1 = t0 + chunk < e ? t0 + chunk : e;
    for (int i = threadIdx.x; i < NBMAX; i += 256) lh[i] = 0;
    __syncthreads();
    for (int i = t0 + threadIdx.x; i < t1; i += 256)
        atomicAdd(&lh[col[i] >> 8], 1);
    __syncthreads();
    for (int b = threadIdx.x; b < NBMAX; b += 256) {
        int c = lh[b];
        if (c) lh[b] = atomicAdd(bcur + b, c);
    }
    __syncthreads();
    for (int i = t0 + threadIdx.x; i < t1; i += 256) {
        int c = col[i];
        int pos = atomicAdd(&lh[c >> 8], 1);
        binbuf[pos] = row[i] | ((c & 255) << 16);
    }
}

__global__ __launch_bounds__(256) void k_build(const int* __restrict__ binbuf,
                                               const int* __restrict__ bbase,
                                               float* __restrict__ dis,
                                               int* __restrict__ rowptr,
                                               ushort* __restrict__ csr, int n) {
    __shared__ int lcnt[256], s[256], cur[256];
    int b = blockIdx.x;
    int t = threadIdx.x;
    int lo = bbase[b], hi = bbase[b + 1];
    int node0 = b << 8;
    int nloc = n - node0 < 256 ? n - node0 : 256;
    lcnt[t] = 0;
    __syncthreads();
    for (int k = lo + t; k < hi; k += 256)
        atomicAdd(&lcnt[(binbuf[k] >> 16) & 255], 1);
    __syncthreads();
    int v = lcnt[t];
    s[t] = v;
    __syncthreads();
    for (int off = 1; off < 256; off <<= 1) {
        int u = (t >= off) ? s[t - off] : 0;
        __syncthreads();
        s[t] += u;
        __syncthreads();
    }
    if (t < nloc) {
        int rp = lo + s[t] - v;
        rowptr[node0 + t] = rp;
        cur[t] = rp;
        dis[node0 + t] = rsqrtf((float)v + 1.0f);
    }
    __syncthreads();
    for (int k = lo + t; k < hi; k += 256) {
        int p = binbuf[k];
        int pos = atomicAdd(&cur[(p >> 16) & 255], 1);
        csr[pos] = (ushort)(p & 0xffff);
    }
}

// x[n,128] @ W[128,64] * dis -> bf16 slabs hs1b[2][n][32]. 64 rows/block.
// W in LDS as [k4][ch] float4 (32KB, lane-consecutive reads, no conflicts);
// x staged per wave in 4 K-stages of 8 float4/row (8KB) -> 40KB = 4 blk/CU.
__global__ __launch_bounds__(256) void k_gemm1(const float* __restrict__ x,
                                               const float* __restrict__ W,
                                               const float* __restrict__ dis,
                                               ushort* __restrict__ hs1b, int n) {
    __shared__ float4 w4[32][64];          // [k4][ch]
    __shared__ float4 xs[4][16][8];        // [wave][row][k4local]
    for (int i = threadIdx.x; i < 128 * 64; i += 256) {
        int k = i >> 6, c = i & 63;
        ((float*)&w4[k >> 2][c])[k & 3] = W[i];
    }
    int wid = threadIdx.x >> 6;
    int lane = threadIdx.x & 63;
    int r0 = blockIdx.x * 64 + wid * 16;
    const float4* x4 = (const float4*)x;
    float acc[16];
#pragma unroll
    for (int r = 0; r < 16; ++r) acc[r] = 0.f;
    __syncthreads();
#pragma unroll
    for (int s = 0; s < 4; ++s) {
        if (s) __syncthreads();            // WAR guard on xs re-stage
#pragma unroll
        for (int j = 0; j < 2; ++j) {
            int idx = j * 64 + lane;       // 0..127: (row, k4l) = (idx>>3, idx&7)
            int rr = r0 + (idx >> 3);
            if (rr >= n) rr = n - 1;
            xs[wid][idx >> 3][idx & 7] = x4[(size_t)rr * 32 + s * 8 + (idx & 7)];
        }
        __syncthreads();
#pragma unroll 2
        for (int k4 = 0; k4 < 8; ++k4) {
            float4 wv = w4[s * 8 + k4][lane];
#pragma unroll
            for (int r = 0; r < 16; ++r) {
                float4 xv = xs[wid][r][k4];   // wave-uniform -> LDS broadcast
                acc[r] = fmaf(xv.x, wv.x, acc[r]);
                acc[r] = fmaf(xv.y, wv.y, acc[r]);
                acc[r] = fmaf(xv.z, wv.z, acc[r]);
                acc[r] = fmaf(xv.w, wv.w, acc[r]);
            }
        }
    }
    ushort* hb = hs1b + (size_t)(lane >> 5) * n * 32 + (lane & 31);
#pragma unroll
    for (int r = 0; r < 16; ++r) {
        int row = r0 + r;
        if (row < n) hb[(size_t)row * 32] = f2bf(dis[row] * acc[r]);
    }
}

// pull1 over one 32-ch bf16 slab: ob = bf16(dis*relu(dis*(self+sum)+b1s))
__global__ __launch_bounds__(256) void k_pull1(const int* __restrict__ rowptr,
                                               const ushort* __restrict__ csr,
                                               const ushort* __restrict__ hb,
                                               const float* __restrict__ dis,
                                               const float* __restrict__ b1s,
                                               ushort* __restrict__ ob, int n) {
    int node = blockIdx.x * 64 + (threadIdx.x >> 2);
    int c4 = threadIdx.x & 3;
    if (node >= n) return;
    const uint4* h4 = (const uint4*)hb;
    int beg = rowptr[node], end = rowptr[node + 1];
    float a[8], b[8];
    uint4 v = h4[(size_t)node * 4 + c4];
    a[0] = bflo(v.x); a[1] = bfhi(v.x); a[2] = bflo(v.y); a[3] = bfhi(v.y);
    a[4] = bflo(v.z); a[5] = bfhi(v.z); a[6] = bflo(v.w); a[7] = bfhi(v.w);
#pragma unroll
    for (int j = 0; j < 8; ++j) b[j] = 0.f;
    int k = beg;
    for (; k + 4 <= end; k += 4) {
        uint4 v0 = h4[(size_t)csr[k] * 4 + c4];
        uint4 v1 = h4[(size_t)csr[k + 1] * 4 + c4];
        uint4 v2 = h4[(size_t)csr[k + 2] * 4 + c4];
        uint4 v3 = h4[(size_t)csr[k + 3] * 4 + c4];
        acc8(a, v0); acc8(b, v1); acc8(a, v2); acc8(b, v3);
    }
    for (; k < end; ++k) acc8(a, h4[(size_t)csr[k] * 4 + c4]);
    float d = dis[node];
    float4 bb0 = *(const float4*)(b1s + c4 * 8);
    float4 bb1 = *(const float4*)(b1s + c4 * 8 + 4);
    float bj[8] = {bb0.x, bb0.y, bb0.z, bb0.w, bb1.x, bb1.y, bb1.z, bb1.w};
    float o[8];
#pragma unroll
    for (int j = 0; j < 8; ++j) {
        float t = fmaf(d, a[j] + b[j], bj[j]);
        o[j] = t > 0.f ? d * t : 0.f;
    }
    uint4 w;
    w.x = (unsigned)f2bf(o[0]) | ((unsigned)f2bf(o[1]) << 16);
    w.y = (unsigned)f2bf(o[2]) | ((unsigned)f2bf(o[3]) << 16);
    w.z = (unsigned)f2bf(o[4]) | ((unsigned)f2bf(o[5]) << 16);
    w.w = (unsigned)f2bf(o[6]) | ((unsigned)f2bf(o[7]) << 16);
    ((uint4*)ob)[(size_t)node * 4 + c4] = w;
}

// pull2 over one slab: og[node*64 + c] = dis*(self+sum), fp32 out for gemm23
__global__ __launch_bounds__(256) void k_pull2(const int* __restrict__ rowptr,
                                               const ushort* __restrict__ csr,
                                               const ushort* __restrict__ hb,
                                               const float* __restrict__ dis,
                                               float* __restrict__ og, int n) {
    int node = blockIdx.x * 64 + (threadIdx.x >> 2);
    int c4 = threadIdx.x & 3;
    if (node >= n) return;
    const uint4* h4 = (const uint4*)hb;
    int beg = rowptr[node], end = rowptr[node + 1];
    float a[8], b[8];
    uint4 v = h4[(size_t)node * 4 + c4];
    a[0] = bflo(v.x); a[1] = bfhi(v.x); a[2] = bflo(v.y); a[3] = bfhi(v.y);
    a[4] = bflo(v.z); a[5] = bfhi(v.z); a[6] = bflo(v.w); a[7] = bfhi(v.w);
#pragma unroll
    for (int j = 0; j < 8; ++j) b[j] = 0.f;
    int k = beg;
    for (; k + 4 <= end; k += 4) {
        uint4 v0 = h4[(size_t)csr[k] * 4 + c4];
        uint4 v1 = h4[(size_t)csr[k + 1] * 4 + c4];
        uint4 v2 = h4[(size_t)csr[k + 2] * 4 + c4];
        uint4 v3 = h4[(size_t)csr[k + 3] * 4 + c4];
        acc8(a, v0); acc8(b, v1); acc8(a, v2); acc8(b, v3);
    }
    for (; k < end; ++k) acc8(a, h4[(size_t)csr[k] * 4 + c4]);
    float d = dis[node];
    float* dst = og + (size_t)node * 64 + c4 * 8;
    *(float4*)dst = make_float4(d * (a[0] + b[0]), d * (a[1] + b[1]),
                                d * (a[2] + b[2]), d * (a[3] + b[3]));
    *(float4*)(dst + 4) = make_float4(d * (a[4] + b[4]), d * (a[5] + b[5]),
                                      d * (a[6] + b[6]), d * (a[7] + b[7]));
}

// g[n,64] @ {W2,W3}[64,32] + bias -> out = mu ++ logvar. 64 rows/block.
__global__ __launch_bounds__(256) void k_gemm23(const float* __restrict__ g,
                                                const float* __restrict__ W2,
                                                const float* __restrict__ b2,
                                                const float* __restrict__ W3,
                                                const float* __restrict__ b3,
                                                float* __restrict__ out, int n) {
    __shared__ float ws[2 * 32 * 17 * 4];  // [half][ch][k4] float4, stride 17
    __shared__ float4 gs[4][16 * 16];      // per-wave 16 rows x 16 float4
    for (int i = threadIdx.x; i < 64 * 32; i += 256) {
        int k = i >> 5, c = i & 31;
        int a = (c * 17 + (k >> 2)) * 4 + (k & 3);
        ws[a] = W2[i];
        ws[2176 + a] = W3[i];
    }
    int wid = threadIdx.x >> 6;
    int lane = threadIdx.x & 63;
    int half = lane >> 5;
    int ch = lane & 31;
    int r0 = blockIdx.x * 64 + wid * 16;
    const float4* g4 = (const float4*)g;
#pragma unroll
    for (int j = 0; j < 4; ++j) {
        int idx = j * 64 + lane;           // (row, k4) = (idx>>4, idx&15)
        int rr = r0 + (idx >> 4);
        if (rr >= n) rr = n - 1;
        gs[wid][idx] = g4[(size_t)rr * 16 + (idx & 15)];
    }
    __syncthreads();
    float acc[16];
#pragma unroll
    for (int r = 0; r < 16; ++r) acc[r] = 0.f;
    const float4* wl = (const float4*)ws;
    const float4* gw = gs[wid];
#pragma unroll 2
    for (int k4 = 0; k4 < 16; ++k4) {
        float4 wv = wl[half * 544 + ch * 17 + k4];
#pragma unroll
        for (int r = 0; r < 16; ++r) {
            float4 gv = gw[r * 16 + k4];   // wave-uniform -> LDS broadcast
            acc[r] = fmaf(gv.x, wv.x, acc[r]);
            acc[r] = fmaf(gv.y, wv.y, acc[r]);
            acc[r] = fmaf(gv.z, wv.z, acc[r]);
            acc[r] = fmaf(gv.w, wv.w, acc[r]);
        }
    }
    float bb = half ? b3[ch] : b2[ch];
    size_t obase = half ? (size_t)n * 32 : 0;
#pragma unroll
    for (int r = 0; r < 16; ++r) {
        int row = r0 + r;
        if (row < n) out[obase + (size_t)row * 32 + ch] = acc[r] + bb;
    }
}

extern "C" void kernel_launch(void* const* d_in, const int* in_sizes, int n_in,
                              void* d_out, int out_size, void* d_ws, size_t ws_size,
                              hipStream_t stream) {
    const float* x  = (const float*)d_in[0];
    const int*   ei = (const int*)d_in[1];
    const float* W1 = (const float*)d_in[2];
    const float* b1 = (const float*)d_in[3];
    const float* W2 = (const float*)d_in[4];
    const float* b2 = (const float*)d_in[5];
    const float* W3 = (const float*)d_in[6];
    const float* b3 = (const float*)d_in[7];

    int n = in_sizes[0] / 128;   // 50000
    int e = in_sizes[1] / 2;     // 1600000
    int nb = (n + 255) >> 8;     // 196 coarse buckets
    const int* row = ei;
    const int* col = ei + e;

    float* fws   = (float*)d_ws;
    float* dis   = fws;                                   // n fp32
    ushort* hs1b = (ushort*)(fws + n);                    // 2 slabs x n x 32 bf16
    ushort* hs2b = hs1b + (size_t)2 * n * 32;             // 2 slabs x n x 32 bf16
    float* gagg  = (float*)(hs2b + (size_t)2 * n * 32);   // n x 64 fp32
    int* binbuf  = (int*)gagg;                            // e ints (dead before pull2)
    int* cnt     = (int*)(gagg + (size_t)n * 64);         // nb
    int* bbase   = cnt + nb;                              // nb+1
    int* bcur    = bbase + nb + 1;                        // nb
    int* rowptr  = bcur + nb;                             // n+1
    ushort* csr  = (ushort*)(rowptr + n + 1);             // e ushorts
    float* out   = (float*)d_out;

    size_t ns32 = (size_t)n * 32;
    int chunk = (e + NTILE - 1) / NTILE;

    dim3 blk(256);
    hipMemsetAsync(cnt, 0, (size_t)nb * 4, stream);
    k_hist<<<NTILE, blk, 0, stream>>>(col, cnt, e);
    k_scanb<<<1, blk, 0, stream>>>(cnt, bbase, bcur, rowptr, nb, n, e);
    k_tilesort<<<NTILE, blk, 0, stream>>>(row, col, bcur, binbuf, e, chunk);
    k_build<<<nb, blk, 0, stream>>>(binbuf, bbase, dis, rowptr, csr, n);

    k_gemm1<<<(n + 63) / 64, blk, 0, stream>>>(x, W1, dis, hs1b, n);

    int pg = (n + 63) / 64;
    k_pull1<<<pg, blk, 0, stream>>>(rowptr, csr, hs1b,        dis, b1,      hs2b,        n);
    k_pull1<<<pg, blk, 0, stream>>>(rowptr, csr, hs1b + ns32, dis, b1 + 32, hs2b + ns32, n);
    k_pull2<<<pg, blk, 0, stream>>>(rowptr, csr, hs2b,        dis, gagg,      n);
    k_pull2<<<pg, blk, 0, stream>>>(rowptr, csr, hs2b + ns32, dis, gagg + 32, n);

    k_gemm23<<<(n + 63) / 64, blk, 0, stream>>>(gagg, W2, b2, W3, b3, out, n);
}

// Round 11
// 178.463 us; speedup vs baseline: 2.8772x; 1.0578x over previous
//
#include <hip/hip_runtime.h>

// GCN VGAE encoder, pull-based. N=50000 (<2^16: ids pack in 16 bits), E=1.6M.
// out[i] = dis[i] * (hs[i] + sum_{j->i} hs[j]),  hs = dis .* (x@W)
// CSR build: coarse-bucket (256 nodes) counting sort, XCD-clean writes;
// tilesort uses 512 tiles (run length ~16 = one 64B line) for occupancy.
// Pulls: bf16 slabs of 32 ch (3.2 MB); merged 2-slab dispatches with
// XCD-pinned slab choice (blockIdx%8 -> XCD; slab = xcd>>2) so each XCD's
// L2 caches exactly one slab. No hipMemsetAsync: graph-captured fill node
// cost ~40us/replay (round 10) -> k_zero kernel instead.
// Bounded unrolls (round 7: full unroll spilled to scratch).

#define NBMAX 256
#define NTILE 512

__device__ __forceinline__ ushort f2bf(float x) {            // RNE fp32->bf16
    unsigned u = __float_as_uint(x);
    u = (u + 0x7FFFu + ((u >> 16) & 1u)) >> 16;
    return (ushort)u;
}
__device__ __forceinline__ float bflo(unsigned u) { return __uint_as_float(u << 16); }
__device__ __forceinline__ float bfhi(unsigned u) { return __uint_as_float(u & 0xFFFF0000u); }

__device__ __forceinline__ void acc8(float* a, uint4 x) {    // a[0..7] += 8 bf16
    a[0] += bflo(x.x); a[1] += bfhi(x.x);
    a[2] += bflo(x.y); a[3] += bfhi(x.y);
    a[4] += bflo(x.z); a[5] += bfhi(x.z);
    a[6] += bflo(x.w); a[7] += bfhi(x.w);
}

__global__ void k_zero(int* __restrict__ cnt, int nb) {
    int i = blockIdx.x * 256 + threadIdx.x;
    if (i < nb) cnt[i] = 0;
}

__global__ __launch_bounds__(256) void k_hist(const int* __restrict__ col,
                                              int* __restrict__ bcnt, int e) {
    __shared__ int h[NBMAX];
    for (int i = threadIdx.x; i < NBMAX; i += 256) h[i] = 0;
    __syncthreads();
    for (int i = blockIdx.x * 256 + threadIdx.x; i < e; i += gridDim.x * 256)
        atomicAdd(&h[col[i] >> 8], 1);
    __syncthreads();
    for (int i = threadIdx.x; i < NBMAX; i += 256)
        if (h[i]) atomicAdd(bcnt + i, h[i]);
}

__global__ __launch_bounds__(256) void k_scanb(const int* __restrict__ bcnt,
                                               int* __restrict__ bbase,
                                               int* __restrict__ bcur,
                                               int* __restrict__ rowptr,
                                               int nb, int n, int e) {
    __shared__ int s[256];
    int t = threadIdx.x;
    int v = (t < nb) ? bcnt[t] : 0;
    s[t] = v;
    __syncthreads();
    for (int off = 1; off < 256; off <<= 1) {
        int u = (t >= off) ? s[t - off] : 0;
        __syncthreads();
        s[t] += u;
        __syncthreads();
    }
    int excl = s[t] - v;
    if (t <= nb) bbase[t] = (t < nb) ? excl : e;
    if (t < nb) bcur[t] = excl;
    if (t == 0) rowptr[n] = e;
}

__global__ __launch_bounds__(256) void k_tilesort(const int* __restrict__ row,
                                                  const int* __restrict__ col,
                                                  int* __restrict__ bcur,
                                                  int* __restrict__ binbuf,
                                                  int e, int chunk) {
    __shared__ int lh[NBMAX];
    int t0 = blockIdx.x * chunk;
    int t1 = t0 + chunk < e ? t0 + chunk : e;
    for (int i = threadIdx.x; i < NBMAX; i += 256) lh[i] = 0;
    __syncthreads();
    for (int i = t0 + threadIdx.x; i < t1; i += 256)
        atomicAdd(&lh[col[i] >> 8], 1);
    __syncthreads();
    for (int b = threadIdx.x; b < NBMAX; b += 256) {
        int c = lh[b];
        if (c) lh[b] = atomicAdd(bcur + b, c);
    }
    __syncthreads();
    for (int i = t0 + threadIdx.x; i < t1; i += 256) {
        int c = col[i];
        int pos = atomicAdd(&lh[c >> 8], 1);
        binbuf[pos] = row[i] | ((c & 255) << 16);
    }
}

__global__ __launch_bounds__(256) void k_build(const int* __restrict__ binbuf,
                                               const int* __restrict__ bbase,
                                               float* __restrict__ dis,
                                               int* __restrict__ rowptr,
                                               ushort* __restrict__ csr, int n) {
    __shared__ int lcnt[256], s[256], cur[256];
    int b = blockIdx.x;
    int t = threadIdx.x;
    int lo = bbase[b], hi = bbase[b + 1];
    int node0 = b << 8;
    int nloc = n - node0 < 256 ? n - node0 : 256;
    lcnt[t] = 0;
    __syncthreads();
    for (int k = lo + t; k < hi; k += 256)
        atomicAdd(&lcnt[(binbuf[k] >> 16) & 255], 1);
    __syncthreads();
    int v = lcnt[t];
    s[t] = v;
    __syncthreads();
    for (int off = 1; off < 256; off <<= 1) {
        int u = (t >= off) ? s[t - off] : 0;
        __syncthreads();
        s[t] += u;
        __syncthreads();
    }
    if (t < nloc) {
        int rp = lo + s[t] - v;
        rowptr[node0 + t] = rp;
        cur[t] = rp;
        dis[node0 + t] = rsqrtf((float)v + 1.0f);
    }
    __syncthreads();
    for (int k = lo + t; k < hi; k += 256) {
        int p = binbuf[k];
        int pos = atomicAdd(&cur[(p >> 16) & 255], 1);
        csr[pos] = (ushort)(p & 0xffff);
    }
}

// x[n,128] @ W[128,64] * dis -> bf16 slabs hs1b[2][n][32]. 64 rows/block.
__global__ __launch_bounds__(256) void k_gemm1(const float* __restrict__ x,
                                               const float* __restrict__ W,
                                               const float* __restrict__ dis,
                                               ushort* __restrict__ hs1b, int n) {
    __shared__ float4 w4[32][64];          // [k4][ch]
    __shared__ float4 xs[4][16][8];        // [wave][row][k4local]
    for (int i = threadIdx.x; i < 128 * 64; i += 256) {
        int k = i >> 6, c = i & 63;
        ((float*)&w4[k >> 2][c])[k & 3] = W[i];
    }
    int wid = threadIdx.x >> 6;
    int lane = threadIdx.x & 63;
    int r0 = blockIdx.x * 64 + wid * 16;
    const float4* x4 = (const float4*)x;
    float acc[16];
#pragma unroll
    for (int r = 0; r < 16; ++r) acc[r] = 0.f;
    __syncthreads();
#pragma unroll
    for (int s = 0; s < 4; ++s) {
        if (s) __syncthreads();            // WAR guard on xs re-stage
#pragma unroll
        for (int j = 0; j < 2; ++j) {
            int idx = j * 64 + lane;       // 0..127: (row, k4l) = (idx>>3, idx&7)
            int rr = r0 + (idx >> 3);
            if (rr >= n) rr = n - 1;
            xs[wid][idx >> 3][idx & 7] = x4[(size_t)rr * 32 + s * 8 + (idx & 7)];
        }
        __syncthreads();
#pragma unroll 2
        for (int k4 = 0; k4 < 8; ++k4) {
            float4 wv = w4[s * 8 + k4][lane];
#pragma unroll
            for (int r = 0; r < 16; ++r) {
                float4 xv = xs[wid][r][k4];   // wave-uniform -> LDS broadcast
                acc[r] = fmaf(xv.x, wv.x, acc[r]);
                acc[r] = fmaf(xv.y, wv.y, acc[r]);
                acc[r] = fmaf(xv.z, wv.z, acc[r]);
                acc[r] = fmaf(xv.w, wv.w, acc[r]);
            }
        }
    }
    ushort* hb = hs1b + (size_t)(lane >> 5) * n * 32 + (lane & 31);
#pragma unroll
    for (int r = 0; r < 16; ++r) {
        int row = r0 + r;
        if (row < n) hb[(size_t)row * 32] = f2bf(dis[row] * acc[r]);
    }
}

// pull1, both slabs in one dispatch. xcd = bid&7 picks slab (xcd>>2) so each
// XCD's L2 caches exactly one 3.2MB slab. 4 lanes/node, uint4 (8 bf16)/lane.
__global__ __launch_bounds__(256) void k_pull1(const int* __restrict__ rowptr,
                                               const ushort* __restrict__ csr,
                                               const ushort* __restrict__ hs1b,
                                               const float* __restrict__ dis,
                                               const float* __restrict__ b1,
                                               ushort* __restrict__ hs2b, int n) {
    int xcd = blockIdx.x & 7;
    int sid = xcd >> 2;
    int idx = (blockIdx.x >> 3) * 4 + (xcd & 3);
    int node = idx * 64 + (threadIdx.x >> 2);
    int c4 = threadIdx.x & 3;
    if (node >= n) return;
    size_t slab = (size_t)sid * n * 32;
    const uint4* h4 = (const uint4*)(hs1b + slab);
    int beg = rowptr[node], end = rowptr[node + 1];
    float a[8], b[8];
    uint4 v = h4[(size_t)node * 4 + c4];
    a[0] = bflo(v.x); a[1] = bfhi(v.x); a[2] = bflo(v.y); a[3] = bfhi(v.y);
    a[4] = bflo(v.z); a[5] = bfhi(v.z); a[6] = bflo(v.w); a[7] = bfhi(v.w);
#pragma unroll
    for (int j = 0; j < 8; ++j) b[j] = 0.f;
    int k = beg;
    for (; k + 4 <= end; k += 4) {
        uint4 v0 = h4[(size_t)csr[k] * 4 + c4];
        uint4 v1 = h4[(size_t)csr[k + 1] * 4 + c4];
        uint4 v2 = h4[(size_t)csr[k + 2] * 4 + c4];
        uint4 v3 = h4[(size_t)csr[k + 3] * 4 + c4];
        acc8(a, v0); acc8(b, v1); acc8(a, v2); acc8(b, v3);
    }
    for (; k < end; ++k) acc8(a, h4[(size_t)csr[k] * 4 + c4]);
    float d = dis[node];
    const float* b1s = b1 + sid * 32;
    float4 bb0 = *(const float4*)(b1s + c4 * 8);
    float4 bb1 = *(const float4*)(b1s + c4 * 8 + 4);
    float bj[8] = {bb0.x, bb0.y, bb0.z, bb0.w, bb1.x, bb1.y, bb1.z, bb1.w};
    float o[8];
#pragma unroll
    for (int j = 0; j < 8; ++j) {
        float t = fmaf(d, a[j] + b[j], bj[j]);
        o[j] = t > 0.f ? d * t : 0.f;
    }
    uint4 w;
    w.x = (unsigned)f2bf(o[0]) | ((unsigned)f2bf(o[1]) << 16);
    w.y = (unsigned)f2bf(o[2]) | ((unsigned)f2bf(o[3]) << 16);
    w.z = (unsigned)f2bf(o[4]) | ((unsigned)f2bf(o[5]) << 16);
    w.w = (unsigned)f2bf(o[6]) | ((unsigned)f2bf(o[7]) << 16);
    ((uint4*)(hs2b + slab))[(size_t)node * 4 + c4] = w;
}

// pull2, both slabs in one dispatch (same XCD-pinned mapping). fp32 out.
__global__ __launch_bounds__(256) void k_pull2(const int* __restrict__ rowptr,
                                               const ushort* __restrict__ csr,
                                               const ushort* __restrict__ hs2b,
                                               const float* __restrict__ dis,
                                               float* __restrict__ gagg, int n) {
    int xcd = blockIdx.x & 7;
    int sid = xcd >> 2;
    int idx = (blockIdx.x >> 3) * 4 + (xcd & 3);
    int node = idx * 64 + (threadIdx.x >> 2);
    int c4 = threadIdx.x & 3;
    if (node >= n) return;
    const uint4* h4 = (const uint4*)(hs2b + (size_t)sid * n * 32);
    int beg = rowptr[node], end = rowptr[node + 1];
    float a[8], b[8];
    uint4 v = h4[(size_t)node * 4 + c4];
    a[0] = bflo(v.x); a[1] = bfhi(v.x); a[2] = bflo(v.y); a[3] = bfhi(v.y);
    a[4] = bflo(v.z); a[5] = bfhi(v.z); a[6] = bflo(v.w); a[7] = bfhi(v.w);
#pragma unroll
    for (int j = 0; j < 8; ++j) b[j] = 0.f;
    int k = beg;
    for (; k + 4 <= end; k += 4) {
        uint4 v0 = h4[(size_t)csr[k] * 4 + c4];
        uint4 v1 = h4[(size_t)csr[k + 1] * 4 + c4];
        uint4 v2 = h4[(size_t)csr[k + 2] * 4 + c4];
        uint4 v3 = h4[(size_t)csr[k + 3] * 4 + c4];
        acc8(a, v0); acc8(b, v1); acc8(a, v2); acc8(b, v3);
    }
    for (; k < end; ++k) acc8(a, h4[(size_t)csr[k] * 4 + c4]);
    float d = dis[node];
    float* dst = gagg + (size_t)node * 64 + sid * 32 + c4 * 8;
    *(float4*)dst = make_float4(d * (a[0] + b[0]), d * (a[1] + b[1]),
                                d * (a[2] + b[2]), d * (a[3] + b[3]));
    *(float4*)(dst + 4) = make_float4(d * (a[4] + b[4]), d * (a[5] + b[5]),
                                      d * (a[6] + b[6]), d * (a[7] + b[7]));
}

// g[n,64] @ {W2,W3}[64,32] + bias -> out = mu ++ logvar. 64 rows/block.
__global__ __launch_bounds__(256) void k_gemm23(const float* __restrict__ g,
                                                const float* __restrict__ W2,
                                                const float* __restrict__ b2,
                                                const float* __restrict__ W3,
                                                const float* __restrict__ b3,
                                                float* __restrict__ out, int n) {
    __shared__ float ws[2 * 32 * 17 * 4];  // [half][ch][k4] float4, stride 17
    __shared__ float4 gs[4][16 * 16];      // per-wave 16 rows x 16 float4
    for (int i = threadIdx.x; i < 64 * 32; i += 256) {
        int k = i >> 5, c = i & 31;
        int a = (c * 17 + (k >> 2)) * 4 + (k & 3);
        ws[a] = W2[i];
        ws[2176 + a] = W3[i];
    }
    int wid = threadIdx.x >> 6;
    int lane = threadIdx.x & 63;
    int half = lane >> 5;
    int ch = lane & 31;
    int r0 = blockIdx.x * 64 + wid * 16;
    const float4* g4 = (const float4*)g;
#pragma unroll
    for (int j = 0; j < 4; ++j) {
        int idx = j * 64 + lane;           // (row, k4) = (idx>>4, idx&15)
        int rr = r0 + (idx >> 4);
        if (rr >= n) rr = n - 1;
        gs[wid][idx] = g4[(size_t)rr * 16 + (idx & 15)];
    }
    __syncthreads();
    float acc[16];
#pragma unroll
    for (int r = 0; r < 16; ++r) acc[r] = 0.f;
    const float4* wl = (const float4*)ws;
    const float4* gw = gs[wid];
#pragma unroll 2
    for (int k4 = 0; k4 < 16; ++k4) {
        float4 wv = wl[half * 544 + ch * 17 + k4];
#pragma unroll
        for (int r = 0; r < 16; ++r) {
            float4 gv = gw[r * 16 + k4];   // wave-uniform -> LDS broadcast
            acc[r] = fmaf(gv.x, wv.x, acc[r]);
            acc[r] = fmaf(gv.y, wv.y, acc[r]);
            acc[r] = fmaf(gv.z, wv.z, acc[r]);
            acc[r] = fmaf(gv.w, wv.w, acc[r]);
        }
    }
    float bb = half ? b3[ch] : b2[ch];
    size_t obase = half ? (size_t)n * 32 : 0;
#pragma unroll
    for (int r = 0; r < 16; ++r) {
        int row = r0 + r;
        if (row < n) out[obase + (size_t)row * 32 + ch] = acc[r] + bb;
    }
}

extern "C" void kernel_launch(void* const* d_in, const int* in_sizes, int n_in,
                              void* d_out, int out_size, void* d_ws, size_t ws_size,
                              hipStream_t stream) {
    const float* x  = (const float*)d_in[0];
    const int*   ei = (const int*)d_in[1];
    const float* W1 = (const float*)d_in[2];
    const float* b1 = (const float*)d_in[3];
    const float* W2 = (const float*)d_in[4];
    const float* b2 = (const float*)d_in[5];
    const float* W3 = (const float*)d_in[6];
    const float* b3 = (const float*)d_in[7];

    int n = in_sizes[0] / 128;   // 50000
    int e = in_sizes[1] / 2;     // 1600000
    int nb = (n + 255) >> 8;     // 196 coarse buckets
    const int* row = ei;
    const int* col = ei + e;

    float* fws   = (float*)d_ws;
    float* dis   = fws;                                   // n fp32
    ushort* hs1b = (ushort*)(fws + n);                    // 2 slabs x n x 32 bf16
    ushort* hs2b = hs1b + (size_t)2 * n * 32;             // 2 slabs x n x 32 bf16
    float* gagg  = (float*)(hs2b + (size_t)2 * n * 32);   // n x 64 fp32
    int* binbuf  = (int*)gagg;                            // e ints (dead before pull2)
    int* cnt     = (int*)(gagg + (size_t)n * 64);         // nb
    int* bbase   = cnt + nb;                              // nb+1
    int* bcur    = bbase + nb + 1;                        // nb
    int* rowptr  = bcur + nb;                             // n+1
    ushort* csr  = (ushort*)(rowptr + n + 1);             // e ushorts
    float* out   = (float*)d_out;

    int chunk = (e + NTILE - 1) / NTILE;
    int pg = (n + 63) / 64;                 // node-blocks per slab
    int pgrid = 8 * ((pg + 3) / 4);         // XCD-pinned 2-slab grid

    dim3 blk(256);
    k_zero<<<(nb + 255) / 256, blk, 0, stream>>>(cnt, nb);
    k_hist<<<NTILE, blk, 0, stream>>>(col, cnt, e);
    k_scanb<<<1, blk, 0, stream>>>(cnt, bbase, bcur, rowptr, nb, n, e);
    k_tilesort<<<NTILE, blk, 0, stream>>>(row, col, bcur, binbuf, e, chunk);
    k_build<<<nb, blk, 0, stream>>>(binbuf, bbase, dis, rowptr, csr, n);

    k_gemm1<<<(n + 63) / 64, blk, 0, stream>>>(x, W1, dis, hs1b, n);
    k_pull1<<<pgrid, blk, 0, stream>>>(rowptr, csr, hs1b, dis, b1, hs2b, n);
    k_pull2<<<pgrid, blk, 0, stream>>>(rowptr, csr, hs2b, dis, gagg, n);
    k_gemm23<<<(n + 63) / 64, blk, 0, stream>>>(gagg, W2, b2, W3, b3, out, n);
}